// Round 6
// baseline (484.676 us; speedup 1.0000x reference)
//
#include <hip/hip_runtime.h>
#include <math.h>

// Problem constants
#define K_CODES   1024
#define D_DIM     256
#define HW_SZ     1024          // 32*32
#define N_TOT     65536         // 64 * 1024
#define ND_TOT    16777216.0f   // N_TOT * D_DIM

// Output layout (float32, concatenated in reference return order)
#define O_ZQ    0
#define O_LOSS  16777216
#define O_IDX   16777217
#define O_CB    16842753
#define O_CS    17104897
#define O_DW    17105921

// Scratch inside the O_ZQ region (float units). ALL dead before k_zt
// overwrites the region with zflat.
#define ZHALF_OFF 0           // 65536x256 f16 = 8388608 floats
#define CHALF_OFF 8388608     // 1024x256 f16  = 131072 floats
#define PK2_OFF   8519680     // 4x65536 i32 second-min key partials
#define PK1_OFF   8781824     // 4x65536 i32 min key partials
#define L1_OFF    9306112     // 65536 f32 row L1 norms (for THR bound)
#define L1R_OFF   9371648     // 65536 f32 actual fp16 residual L1
// Scratch in the O_DW tail (262144 floats, survives k_zt; dead before k_dwsum):
//   ZN     65536 f32 at out+O_DW
//   FLAG   65536 int at +65536   (list A from front, list B from back)
//   CANDLO 65536 int at +131072  (k0 | k1<<16 per A entry)
//   CANDHI 65536 int at +196608  (k2 | k3<<16 per A entry)

typedef float f2 __attribute__((ext_vector_type(2)));
typedef float f32x4 __attribute__((ext_vector_type(4)));
typedef _Float16 f16;
typedef _Float16 f16x8 __attribute__((ext_vector_type(8)));
typedef _Float16 f16x4 __attribute__((ext_vector_type(4)));

__device__ __forceinline__ int imin(int a, int b) { return a < b ? a : b; }
__device__ __forceinline__ int imax(int a, int b) { return a > b ? a : b; }

// ---------------------------------------------------------------------------
// Transpose codebook [K][D] -> CT [D][K] (for rescueB's register GEMM).
__global__ void k_transpose(const float* __restrict__ cb, float* __restrict__ ct) {
    __shared__ float tile[32][33];
    int k0 = blockIdx.x * 32;
    int d0 = blockIdx.y * 32;
    int c = threadIdx.x & 31, r0 = threadIdx.x >> 5;
#pragma unroll
    for (int p = 0; p < 4; ++p) {
        int r = r0 + p * 8;
        tile[r][c] = cb[(k0 + r) * D_DIM + d0 + c];
    }
    __syncthreads();
#pragma unroll
    for (int p = 0; p < 4; ++p) {
        int r = r0 + p * 8;
        ct[(size_t)(d0 + r) * K_CODES + k0 + c] = tile[c][r];
    }
}

// ---------------------------------------------------------------------------
// Per-code squared norms, numpy-pairwise fp32 semantics (contract OFF).
__global__ void k_cnorm(const float* __restrict__ cb, float* __restrict__ cn) {
#pragma clang fp contract(off)
    int k = blockIdx.x * 256 + threadIdx.x;            // grid = 4 blocks
    const float* row = cb + (size_t)k * D_DIM;
    float s1 = 0.f, s2 = 0.f;
#pragma unroll
    for (int blk = 0; blk < 2; ++blk) {
        const float* p = row + blk * 128;
        float r[8];
#pragma unroll
        for (int j = 0; j < 8; ++j) { float v = p[j]; r[j] = v * v; }
        for (int i = 8; i < 128; i += 8) {
#pragma unroll
            for (int j = 0; j < 8; ++j) { float v = p[i + j]; r[j] = r[j] + v * v; }
        }
        float s = ((r[0] + r[1]) + (r[2] + r[3])) + ((r[4] + r[5]) + (r[6] + r[7]));
        if (blk == 0) s1 = s; else s2 = s;
    }
    cn[k] = s1 + s2;
}

// ---------------------------------------------------------------------------
// Per-row squared norms (bit-identical fold) + L1 norms (feeds THR bound).
// Also zero-inits the L1R residual accumulator (prep_z atomically adds).
__global__ void k_zn2(const float* __restrict__ ze, float* __restrict__ zn,
                      float* __restrict__ l1, float* __restrict__ l1r) {
#pragma clang fp contract(off)
    int n = blockIdx.x * 256 + threadIdx.x;            // grid = 256 blocks
    int b = n >> 10, hw = n & 1023;
    const float* p = ze + (size_t)b * (D_DIM * HW_SZ) + hw;
    float s1 = 0.f, s2 = 0.f, a1 = 0.f;
#pragma unroll
    for (int blk = 0; blk < 2; ++blk) {
        const float* q = p + (size_t)(blk * 128) * HW_SZ;
        float r[8], qa[8];
#pragma unroll
        for (int j = 0; j < 8; ++j) {
            float v = q[(size_t)j * HW_SZ];
            r[j] = v * v; qa[j] = fabsf(v);
        }
        for (int i = 8; i < 128; i += 8) {
#pragma unroll
            for (int j = 0; j < 8; ++j) {
                float v = q[(size_t)(i + j) * HW_SZ];
                r[j] = r[j] + v * v;
                qa[j] = qa[j] + fabsf(v);
            }
        }
        float s = ((r[0] + r[1]) + (r[2] + r[3])) + ((r[4] + r[5]) + (r[6] + r[7]));
        a1 += ((qa[0] + qa[1]) + (qa[2] + qa[3])) + ((qa[4] + qa[5]) + (qa[6] + qa[7]));
        if (blk == 0) s1 = s; else s2 = s;
    }
    zn[n] = s1 + s2;
    l1[n] = a1;
    l1r[n] = 0.f;
}

// ---------------------------------------------------------------------------
// Codebook -> fp16, scaled by 2^10 (exact pow2; keeps values in [-1,1]).
__global__ __launch_bounds__(256)
void k_prep_c(const float* __restrict__ cb, f16* __restrict__ ch) {
    int i = (blockIdx.x * 256 + threadIdx.x) * 4;      // grid = 256 blocks
    float4 v = *(const float4*)(cb + i);
    f16x4 h;
    h[0] = (f16)(v.x * 1024.0f);
    h[1] = (f16)(v.y * 1024.0f);
    h[2] = (f16)(v.z * 1024.0f);
    h[3] = (f16)(v.w * 1024.0f);
    *(f16x4*)(ch + i) = h;
}

// ---------------------------------------------------------------------------
// z_e [64][256][1024] NCHW -> zhalf [65536][256] row-major fp16.
// Also accumulates the ACTUAL per-row fp16 conversion residual
// L1r(n) = sum_d |z - fl16(z)| (drives the tight rescue threshold).
__global__ __launch_bounds__(256)
void k_prep_z(const float* __restrict__ ze, f16* __restrict__ zh,
              float* __restrict__ l1r) {
    __shared__ float tile[64][65];
    const int t = threadIdx.x;
    const int hw0 = blockIdx.x * 64;
    const int d0  = blockIdx.y * 64;
    const int b   = blockIdx.z;
    const size_t base_in = (size_t)b * (D_DIM * HW_SZ);
#pragma unroll
    for (int p = 0; p < 4; ++p) {
        int dd = p * 16 + (t >> 4);
        int c4 = (t & 15) * 4;
        float4 v = *(const float4*)(ze + base_in + (size_t)(d0 + dd) * HW_SZ + hw0 + c4);
        tile[dd][c4 + 0] = v.x;
        tile[dd][c4 + 1] = v.y;
        tile[dd][c4 + 2] = v.z;
        tile[dd][c4 + 3] = v.w;
    }
    __syncthreads();
#pragma unroll
    for (int p = 0; p < 4; ++p) {
        int hh  = p * 16 + (t >> 4);
        int dc4 = (t & 15) * 4;
        float v0 = tile[dc4 + 0][hh], v1 = tile[dc4 + 1][hh];
        float v2 = tile[dc4 + 2][hh], v3 = tile[dc4 + 3][hh];
        f16x4 h;
        h[0] = (f16)v0; h[1] = (f16)v1; h[2] = (f16)v2; h[3] = (f16)v3;
        *(f16x4*)(zh + (size_t)(b * HW_SZ + hw0 + hh) * D_DIM + d0 + dc4) = h;
        float rs = fabsf(v0 - (float)h[0]) + fabsf(v1 - (float)h[1])
                 + fabsf(v2 - (float)h[2]) + fabsf(v3 - (float)h[3]);
        rs += __shfl_down(rs, 8, 64);
        rs += __shfl_down(rs, 4, 64);
        rs += __shfl_down(rs, 2, 64);
        rs += __shfl_down(rs, 1, 64);
        if ((t & 15) == 0)
            atomicAdd(&l1r[b * HW_SZ + hw0 + hh], rs);
    }
}

// ---------------------------------------------------------------------------
// MFMA argmin: grid = (512 n-tiles, 4 k-chunks). i32 packed-key epilogue.
__global__ __launch_bounds__(256, 2)
void k_margmin(const f16* __restrict__ zh, const f16* __restrict__ ch,
               const float* __restrict__ cn,
               int* __restrict__ pk1, int* __restrict__ pk2) {
    __shared__ __align__(16) char smem[49152];
    f16* Al = (f16*)smem;               // [128*64] 16 KB
    f16* Bl = (f16*)(smem + 16384);     // [256*64] 32 KB
    const int t  = threadIdx.x;
    const int w  = t >> 6;       // wave (0..3)
    const int l  = t & 63;       // lane
    const int kc = blockIdx.y;   // k-chunk
    const int n0 = blockIdx.x * 128;
    const int rl = l >> 3;       // staging: row-within-8
    const int gg = l & 7;        // staging: granule
    const int gq = l >> 4;       // frag: quarter-wave group
    const int rr = l & 15;       // frag: row/col within frag

    f32x4 acc[8][4];
#pragma unroll
    for (int a = 0; a < 8; ++a)
#pragma unroll
        for (int b = 0; b < 4; ++b) acc[a][b] = (f32x4)0.f;

    for (int d0 = 0; d0 < 256; d0 += 64) {
        __syncthreads();   // previous iteration's frag reads done
        // stage A (z): 128 rows x 64 d, source granule pre-swizzled
#pragma unroll
        for (int i = 0; i < 4; ++i) {
            int row = w * 32 + i * 8 + rl;
            const f16* g = zh + (size_t)(n0 + row) * D_DIM + d0 + 8 * (gg ^ (row & 7));
            __builtin_amdgcn_global_load_lds(
                (const __attribute__((address_space(1))) void*)g,
                (__attribute__((address_space(3))) void*)(smem + (w * 32 + i * 8) * 128),
                16, 0, 0);
        }
        // stage B (codebook): 256 rows x 64 d
#pragma unroll
        for (int i = 0; i < 8; ++i) {
            int row = w * 64 + i * 8 + rl;
            const f16* g = ch + (size_t)(kc * 256 + row) * D_DIM + d0 + 8 * (gg ^ (row & 7));
            __builtin_amdgcn_global_load_lds(
                (const __attribute__((address_space(1))) void*)g,
                (__attribute__((address_space(3))) void*)(smem + 16384 + row * 128),
                16, 0, 0);
        }
        __syncthreads();
#pragma unroll
        for (int ks = 0; ks < 2; ++ks) {
            f16x8 af[8], bf[4];
#pragma unroll
            for (int nf = 0; nf < 8; ++nf) {
                int row = nf * 16 + rr;
                af[nf] = *(const f16x8*)((char*)Al + row * 128 +
                                         16 * ((ks * 4 + gq) ^ (row & 7)));
            }
#pragma unroll
            for (int kf = 0; kf < 4; ++kf) {
                int row = w * 64 + kf * 16 + rr;
                bf[kf] = *(const f16x8*)((char*)Bl + row * 128 +
                                         16 * ((ks * 4 + gq) ^ (row & 7)));
            }
#pragma unroll
            for (int nf = 0; nf < 8; ++nf)
#pragma unroll
                for (int kf = 0; kf < 4; ++kf)
                    acc[nf][kf] = __builtin_amdgcn_mfma_f32_16x16x32_f16(
                        af[nf], bf[kf], acc[nf][kf], 0, 0, 0);
        }
    }
    __syncthreads();   // all frag reads done before smem reuse

    // Epilogue: packed i32 keys. acc = 1024*G (codebook pre-scale), so
    // t*2^21 = cn*2^21 - acc*2^12.  |t| <= 0.49 -> |tq| < 2^21, key fits i32.
    int* ep = (int*)smem;   // [128][66] ints = 33.8 KB
    float cnq[4];
    int   kk4[4];
#pragma unroll
    for (int kf = 0; kf < 4; ++kf) {
        int k = kc * 256 + w * 64 + kf * 16 + rr;
        kk4[kf] = k;
        cnq[kf] = cn[k] * 0x1p21f;
    }
#pragma unroll
    for (int nf = 0; nf < 8; ++nf) {
#pragma unroll
        for (int r = 0; r < 4; ++r) {
            int m1 = 0x7FFFFFFF, m2 = 0x7FFFFFFF;
#pragma unroll
            for (int kf = 0; kf < 4; ++kf) {
                float tqf = fmaf(acc[nf][kf][r], -0x1p12f, cnq[kf]);
                int key = ((int)tqf << 10) + kk4[kf];
                int mx = imax(m1, key);
                m1 = imin(m1, key);
                m2 = imin(m2, mx);
            }
            // one xor-step: merge lane pairs (rr even|odd)
            int o1 = __shfl_xor(m1, 1, 64);
            int o2 = __shfl_xor(m2, 1, 64);
            int mx = imax(m1, o1);
            m1 = imin(m1, o1);
            m2 = imin(imin(m2, o2), mx);
            if ((rr & 1) == 0) {
                int row = nf * 16 + gq * 4 + r;
                int p   = w * 8 + (rr >> 1);
                *(int2*)&ep[row * 66 + p * 2] = make_int2(m1, m2);
            }
        }
    }
    __syncthreads();
    if (t < 128) {
        int m1 = 0x7FFFFFFF, m2 = 0x7FFFFFFF;
        const int2* rp = (const int2*)&ep[t * 66];
#pragma unroll 8
        for (int p = 0; p < 32; ++p) {
            int2 a = rp[p];
            int mx = imax(m1, a.x);
            m1 = imin(m1, a.x);
            m2 = imin(imin(m2, a.y), mx);
        }
        pk1[kc * N_TOT + n0 + t] = m1;
        pk2[kc * N_TOT + n0 + t] = m2;
    }
}

// ---------------------------------------------------------------------------
// Combine 4 chunk key partials. Three outcomes per row:
//   certain:  global m2 gap > THR                       -> done
//   cheap A:  every chunk's m2 gap > THR                -> exact argmin is
//             provably among the 4 chunk argmins; emit row + packed cands
//   full  B:  some chunk holds 2 near-candidates        -> full 1024 rescue
// THR (sound): l1*1.05e-6 (c-side fp16) + L1r*2.25e-3 (actual z residual)
//             + 2.2e-4 (fold/quant slops).
__global__ __launch_bounds__(256)
void k_combine4(const int* __restrict__ pk1, const int* __restrict__ pk2,
                const float* __restrict__ l1b, const float* __restrict__ l1rb,
                float* __restrict__ out_idx, float* __restrict__ counts,
                int* __restrict__ flag, int* __restrict__ candlo,
                int* __restrict__ candhi,
                int* __restrict__ flagn, int* __restrict__ flagnB) {
    int n = blockIdx.x * 256 + threadIdx.x;
    int a1[4], a2[4];
    int m1 = 0x7FFFFFFF, m2 = 0x7FFFFFFF;
#pragma unroll
    for (int c = 0; c < 4; ++c) {
        a1[c] = pk1[c * N_TOT + n];
        a2[c] = pk2[c * N_TOT + n];
        int mx = imax(m1, a1[c]);
        m1 = imin(m1, a1[c]);
        m2 = imin(imin(m2, a2[c]), mx);
    }
    int i1 = m1 & 1023;
    out_idx[n] = (float)i1;
    atomicAdd(counts + i1, 1.0f);
    int t1 = m1 >> 10;
    float thr = fmaf(l1b[n], 1.05e-6f, fmaf(l1rb[n], 2.25e-3f, 2.2e-4f));
    int thrq = (int)(thr * 0x1p21f);
    if ((m2 >> 10) - t1 > thrq) return;           // certain
    bool full = false;
#pragma unroll
    for (int c = 0; c < 4; ++c)
        if ((a2[c] >> 10) - t1 <= thrq) full = true;
    if (!full) {
        int p = atomicAdd(flagn, 1);
        flag[p] = n;
        candlo[p] = (a1[0] & 1023) | ((a1[1] & 1023) << 16);
        candhi[p] = (a1[2] & 1023) | ((a1[3] & 1023) << 16);
    } else {
        int p = atomicAdd(flagnB, 1);
        flag[65535 - p] = n;
    }
}

// ---------------------------------------------------------------------------
// Transpose z_e [64][256][1024] -> zflat [65536][256] (into O_ZQ region,
// overwriting the dead fp16/partial scratch; runs BEFORE the rescues).
__global__ __launch_bounds__(256)
void k_zt(const float* __restrict__ ze, float* __restrict__ zflat) {
    __shared__ float tile[64][65];
    const int t = threadIdx.x;
    const int hw0 = blockIdx.x * 64;
    const int d0  = blockIdx.y * 64;
    const int b   = blockIdx.z;
    const size_t base_in = (size_t)b * (D_DIM * HW_SZ);
#pragma unroll
    for (int p = 0; p < 4; ++p) {
        int dd = p * 16 + (t >> 4);
        int c4 = (t & 15) * 4;
        float4 v = *(const float4*)(ze + base_in + (size_t)(d0 + dd) * HW_SZ + hw0 + c4);
        tile[dd][c4 + 0] = v.x;
        tile[dd][c4 + 1] = v.y;
        tile[dd][c4 + 2] = v.z;
        tile[dd][c4 + 3] = v.w;
    }
    __syncthreads();
#pragma unroll
    for (int p = 0; p < 4; ++p) {
        int hh  = p * 16 + (t >> 4);
        int dc4 = (t & 15) * 4;
        float4 v = { tile[dc4 + 0][hh], tile[dc4 + 1][hh],
                     tile[dc4 + 2][hh], tile[dc4 + 3][hh] };
        *(float4*)(zflat + (size_t)(b * HW_SZ + hw0 + hh) * D_DIM + d0 + dc4) = v;
    }
}

// ---------------------------------------------------------------------------
// Rescue A: exact rescore of ONLY the 4 chunk-argmin candidates per flagged
// row. One thread per (row, candidate): scalar fmaf chain over ascending d
// (bit-identical exact arithmetic), s = fl(zn - 2G) + cn, quad-shuffle
// lexicographic (s, k) min (k ascending across the quad = chunk order).
__global__ __launch_bounds__(256)
void k_rescueA(const float* __restrict__ zflat, const float* __restrict__ cb,
               const float* __restrict__ cn, const float* __restrict__ znb,
               const int* __restrict__ flag, const int* __restrict__ candlo,
               const int* __restrict__ candhi, const int* __restrict__ flagn,
               float* __restrict__ out_idx, float* __restrict__ counts) {
    const int nA = *flagn;
    const int t = threadIdx.x;
    const int c = t & 3;
    const int r = t >> 2;
    for (int g = blockIdx.x; g * 64 < nA; g += 1024) {
        int i = g * 64 + r;
        bool act = i < nA;
        int ii = act ? i : 0;
        int n = flag[ii];
        int word = (c < 2) ? candlo[ii] : candhi[ii];
        int k = (c & 1) ? ((word >> 16) & 0xFFFF) : (word & 0xFFFF);
        const float* zp = zflat + (size_t)n * D_DIM;
        const float* cp = cb + (size_t)k * D_DIM;
        float acc = 0.f;
        for (int d = 0; d < 256; d += 8) {
            float4 z0 = *(const float4*)(zp + d);
            float4 z1 = *(const float4*)(zp + d + 4);
            float4 c0 = *(const float4*)(cp + d);
            float4 c1 = *(const float4*)(cp + d + 4);
            acc = fmaf(z0.x, c0.x, acc); acc = fmaf(z0.y, c0.y, acc);
            acc = fmaf(z0.z, c0.z, acc); acc = fmaf(z0.w, c0.w, acc);
            acc = fmaf(z1.x, c1.x, acc); acc = fmaf(z1.y, c1.y, acc);
            acc = fmaf(z1.z, c1.z, acc); acc = fmaf(z1.w, c1.w, acc);
        }
        float s = (znb[n] - 2.0f * acc) + cn[k];
        // lexicographic min across the quad (k strictly ascending in c)
        for (int off = 1; off < 4; off <<= 1) {
            float os = __shfl_xor(s, off, 64);
            int   ok = __shfl_xor(k, off, 64);
            if (os < s || (os == s && ok < k)) { s = os; k = ok; }
        }
        if (act && c == 0) {
            int old = (int)out_idx[n];
            if (k != old) {
                out_idx[n] = (float)k;
                atomicAdd(counts + old, -1.0f);
                atomicAdd(counts + k,  1.0f);
            }
        }
    }
}

// ---------------------------------------------------------------------------
// Rescue B: full 1024-code exact rescore for rows where one chunk holds two
// near-candidates (rare). 16 rows/group; CT streamed from L2 with issue-early
// prefetch; per-code chains are sequential pk-fma over ascending d.
__global__ __launch_bounds__(256)
void k_rescueB(const float* __restrict__ zflat, const float* __restrict__ ct,
               const float* __restrict__ cn, const float* __restrict__ znb,
               const int* __restrict__ flag, const int* __restrict__ flagnB,
               float* __restrict__ out_idx, float* __restrict__ counts) {
    __shared__ float zl[16][256];    // [row][d]; broadcast reads (16 KB)
    __shared__ float znl[16];
    __shared__ float cnl[1024];
    __shared__ float redv[4][16];
    __shared__ int   redi[4][16];
    __shared__ int   rows[16];
    const int t  = threadIdx.x;
    const int w  = t >> 6;           // wave: codes w*256 .. w*256+255
    const int tx = t & 63;           // lane: codes w*256 + tx*4 .. +3
    const int nB = *flagnB;
#pragma unroll
    for (int i = 0; i < 4; ++i) cnl[i * 256 + t] = cn[i * 256 + t];

    const float* cbase = ct + w * 256 + tx * 4;
    const int kbase = w * 256 + tx * 4;

#define LD(i) (*(const float4*)(cbase + (size_t)(i) * K_CODES))

    for (int grp = blockIdx.x; grp * 16 < nB; grp += 256) {
        __syncthreads();             // prev group fully done (zl/rows reuse)
        if (t < 16) {
            int ii = grp * 16 + t;
            int n = flag[65535 - (ii < nB ? ii : 0)];
            rows[t] = n;
            znl[t] = znb[n];
        }
        __syncthreads();
#pragma unroll
        for (int r = 0; r < 16; ++r)
            zl[r][t] = zflat[(size_t)rows[r] * D_DIM + t];
        __syncthreads();

        f2 acc[16][2];
#pragma unroll
        for (int r = 0; r < 16; ++r) { acc[r][0] = (f2)0.f; acc[r][1] = (f2)0.f; }

        float4 p0 = LD(0), p1 = LD(1), p2 = LD(2), p3 = LD(3);
        for (int d = 0; d < 256; d += 4) {
            float4 q0 = LD(d + 4), q1 = LD(d + 5), q2 = LD(d + 6), q3 = LD(d + 7);
#pragma unroll
            for (int h = 0; h < 2; ++h) {
                float4 zr[8];
#pragma unroll
                for (int r = 0; r < 8; ++r)
                    zr[r] = *(const float4*)&zl[h * 8 + r][d];
#pragma unroll
                for (int r = 0; r < 8; ++r) {
                    int rr = h * 8 + r;
                    f2 zx = { zr[r].x, zr[r].x };
                    acc[rr][0] = __builtin_elementwise_fma(zx, (f2){p0.x, p0.y}, acc[rr][0]);
                    acc[rr][1] = __builtin_elementwise_fma(zx, (f2){p0.z, p0.w}, acc[rr][1]);
                    f2 zy = { zr[r].y, zr[r].y };
                    acc[rr][0] = __builtin_elementwise_fma(zy, (f2){p1.x, p1.y}, acc[rr][0]);
                    acc[rr][1] = __builtin_elementwise_fma(zy, (f2){p1.z, p1.w}, acc[rr][1]);
                    f2 zz = { zr[r].z, zr[r].z };
                    acc[rr][0] = __builtin_elementwise_fma(zz, (f2){p2.x, p2.y}, acc[rr][0]);
                    acc[rr][1] = __builtin_elementwise_fma(zz, (f2){p2.z, p2.w}, acc[rr][1]);
                    f2 zw = { zr[r].w, zr[r].w };
                    acc[rr][0] = __builtin_elementwise_fma(zw, (f2){p3.x, p3.y}, acc[rr][0]);
                    acc[rr][1] = __builtin_elementwise_fma(zw, (f2){p3.z, p3.w}, acc[rr][1]);
                }
            }
            p0 = q0; p1 = q1; p2 = q2; p3 = q3;
        }

#pragma unroll
        for (int r = 0; r < 16; ++r) {
            float znv = znl[r];
            float a0 = acc[r][0].x, a1 = acc[r][0].y;
            float a2 = acc[r][1].x, a3 = acc[r][1].y;
            float bs; int bk;
            {
                float s0 = (znv - 2.0f * a0) + cnl[kbase + 0];
                float s1 = (znv - 2.0f * a1) + cnl[kbase + 1];
                float s2 = (znv - 2.0f * a2) + cnl[kbase + 2];
                float s3 = (znv - 2.0f * a3) + cnl[kbase + 3];
                bs = s0; bk = kbase;
                if (s1 < bs) { bs = s1; bk = kbase + 1; }
                if (s2 < bs) { bs = s2; bk = kbase + 2; }
                if (s3 < bs) { bs = s3; bk = kbase + 3; }
            }
            for (int off = 1; off < 64; off <<= 1) {
                float os = __shfl_xor(bs, off, 64);
                int   ok = __shfl_xor(bk, off, 64);
                if (os < bs || (os == bs && ok < bk)) { bs = os; bk = ok; }
            }
            if (tx == 0) { redv[w][r] = bs; redi[w][r] = bk; }
        }
        __syncthreads();
        if (t < 16 && grp * 16 + t < nB) {
            float bs = redv[0][t]; int bk = redi[0][t];
#pragma unroll
            for (int w2 = 1; w2 < 4; ++w2) {
                float os = redv[w2][t];   // ascending wave = ascending k
                int   ok = redi[w2][t];
                if (os < bs) { bs = os; bk = ok; }
            }
            int n = rows[t];
            int old = (int)out_idx[n];
            if (old != bk) {
                out_idx[n] = (float)bk;
                atomicAdd(counts + old, -1.0f);
                atomicAdd(counts + bk,  1.0f);
            }
        }
    }
#undef LD
}

// ---------------------------------------------------------------------------
// EMA cluster size + smoothed (loss finalize lives in k_zq).
__global__ __launch_bounds__(1024)
void k_ema_cs(const float* __restrict__ ema_cs, const float* __restrict__ counts,
              float* __restrict__ out_cs, float* __restrict__ smoothed) {
    __shared__ float red[1024];
    int k = threadIdx.x;
    float cs_new = fmaf(0.99f, ema_cs[k], 0.01f * counts[k]);
    red[k] = cs_new;
    __syncthreads();
    for (int off = 512; off > 0; off >>= 1) {
        if (k < off) red[k] += red[k + off];
        __syncthreads();
    }
    float ntot = red[0];
    out_cs[k] = cs_new;
    smoothed[k] = (cs_new + 1e-5f) / (ntot + 0.01024f) * ntot;
}

// ---------------------------------------------------------------------------
// Per-code segment sum: one block per code; compact matching rows into an LDS
// queue (float4 index scan), sum rows coalesced from zflat with 2-way load
// ILP. Fuses loss partials + dw EMA + cb write.
__global__ __launch_bounds__(256)
void k_dwsum(const float* __restrict__ idxf, const float* __restrict__ zflat,
             const float* __restrict__ cb, const float* __restrict__ ema_dw,
             const float* __restrict__ smoothed, float* __restrict__ out_dw,
             float* __restrict__ out_cb, float* __restrict__ lossacc) {
    __shared__ int queue[4096];
    __shared__ int qn;
    __shared__ float lred[4];

    const int k = blockIdx.x;
    const int t = threadIdx.x;
    const float fk = (float)k;
    const float ck = cb[(size_t)k * D_DIM + t];

    float acc = 0.f;
    float ls  = 0.f;

    for (int chunk = 0; chunk < 16; ++chunk) {
        if (t == 0) qn = 0;
        __syncthreads();
#pragma unroll
        for (int j = 0; j < 4; ++j) {
            int nb = chunk * 4096 + j * 1024 + t * 4;   // coalesced float4 scan
            float4 iv = *(const float4*)(idxf + nb);
            if (iv.x == fk) { int p = atomicAdd(&qn, 1); queue[p] = nb; }
            if (iv.y == fk) { int p = atomicAdd(&qn, 1); queue[p] = nb + 1; }
            if (iv.z == fk) { int p = atomicAdd(&qn, 1); queue[p] = nb + 2; }
            if (iv.w == fk) { int p = atomicAdd(&qn, 1); queue[p] = nb + 3; }
        }
        __syncthreads();
        int m = qn;
        int i = 0;
        for (; i + 1 < m; i += 2) {                    // 2-way load ILP
            int n1 = queue[i], n2 = queue[i + 1];
            float z1 = zflat[(size_t)n1 * D_DIM + t];
            float z2 = zflat[(size_t)n2 * D_DIM + t];
            acc += z1; float d1 = ck - z1; ls += d1 * d1;
            acc += z2; float d2 = ck - z2; ls += d2 * d2;
        }
        if (i < m) {
            int n1 = queue[i];
            float z1 = zflat[(size_t)n1 * D_DIM + t];
            acc += z1; float d1 = ck - z1; ls += d1 * d1;
        }
        __syncthreads();   // all queue reads done before next chunk's writes
    }

    size_t o = (size_t)k * D_DIM + t;
    float nd = fmaf(0.99f, ema_dw[o], 0.01f * acc);
    out_dw[o] = nd;
    out_cb[o] = nd / smoothed[k];

#pragma unroll
    for (int off = 32; off > 0; off >>= 1) ls += __shfl_down(ls, off, 64);
    if ((t & 63) == 0) lred[t >> 6] = ls;
    __syncthreads();
    if (t == 0) atomicAdd(lossacc, lred[0] + lred[1] + lred[2] + lred[3]);
}

// ---------------------------------------------------------------------------
// Straight-through z_q writer: pure float4 stream + L2 codebook gather.
// Grid 1024 blocks; each block covers a 16-d slice.
__global__ __launch_bounds__(256)
void k_zq(const float* __restrict__ ze, const float* __restrict__ cb,
          const float* __restrict__ idxf, float* __restrict__ out0,
          const float* __restrict__ lossacc, float* __restrict__ out_loss) {
    const int t = threadIdx.x;
    int q   = blockIdx.x & 3;                  // d-16 segment
    int g   = (blockIdx.x >> 2) * 64 + (t & 63);   // hw4-group id in [0, 16384)
    int b   = g >> 8;
    int hwl = (g & 255) * 4;
    int dg  = t >> 6;                          // d-quarter (0..3)
    const size_t base = (size_t)b * (D_DIM * HW_SZ) + hwl;

    int i0 = (int)idxf[b * HW_SZ + hwl + 0];
    int i1 = (int)idxf[b * HW_SZ + hwl + 1];
    int i2 = (int)idxf[b * HW_SZ + hwl + 2];
    int i3 = (int)idxf[b * HW_SZ + hwl + 3];
    const float* c0 = cb + (size_t)i0 * D_DIM;
    const float* c1 = cb + (size_t)i1 * D_DIM;
    const float* c2 = cb + (size_t)i2 * D_DIM;
    const float* c3 = cb + (size_t)i3 * D_DIM;

#pragma unroll 4
    for (int i = 0; i < 16; ++i) {
        int d = dg * 64 + q * 16 + i;
        size_t o = base + (size_t)d * HW_SZ;
        float4 z = *(const float4*)(ze + o);
        float4 r;
        r.x = z.x + (c0[d] - z.x);
        r.y = z.y + (c1[d] - z.y);
        r.z = z.z + (c2[d] - z.z);
        r.w = z.w + (c3[d] - z.w);
        *(float4*)(out0 + o) = r;
    }

    if (blockIdx.x == 0 && t == 0)
        out_loss[0] = 0.5f * lossacc[0] / ND_TOT;
}

// ---------------------------------------------------------------------------
extern "C" void kernel_launch(void* const* d_in, const int* in_sizes, int n_in,
                              void* d_out, int out_size, void* d_ws, size_t ws_size,
                              hipStream_t stream) {
    const float* ze     = (const float*)d_in[0];  // [64,256,32,32]
    const float* cb     = (const float*)d_in[1];  // [1024,256]
    const float* emacs  = (const float*)d_in[2];  // [1024]
    const float* emadw  = (const float*)d_in[3];  // [1024,256]
    float* out = (float*)d_out;
    float* ws  = (float*)d_ws;

    // Scratch choreography (stream-ordered reuse of d_out):
    //   O_ZQ region: ZH/CH (prep -> margmin), PK1/PK2 (margmin -> combine4),
    //     L1/L1R (zn2/prep_z -> combine4) — all dead before k_zt writes zflat;
    //     zflat (zt -> rescueA/B/dwsum) — overwritten by k_zq at the end.
    //   Tail O_CB: CT (transpose -> rescueB, then out_cb by dwsum).
    //   Tail O_DW (262144 = 4x65536): ZN | FLAG(A front/B back) | CANDLO |
    //     CANDHI (combine4 -> rescueA/B, then out_dw by dwsum).
    f16*   ZH     = (f16*)(out + ZHALF_OFF);
    f16*   CH     = (f16*)(out + CHALF_OFF);
    int*   PK2    = (int*)(out + PK2_OFF);
    int*   PK1    = (int*)(out + PK1_OFF);
    float* L1b    = out + L1_OFF;
    float* L1R    = out + L1R_OFF;
    float* ZFLAT  = out;
    float* CT     = out + O_CB;
    float* ZNb    = out + O_DW;
    int*   FLAG   = (int*)(out + O_DW + 65536);
    int*   CANDLO = (int*)(out + O_DW + 131072);
    int*   CANDHI = (int*)(out + O_DW + 196608);
    // d_ws scratch
    float* counts   = ws;                 // 1024
    float* lossacc  = ws + 1024;          // 1
    int*   flagn    = (int*)(ws + 1025);  // 1
    int*   flagnB   = (int*)(ws + 1026);  // 1
    float* smoothed = ws + 1088;          // 1024
    float* CN       = ws + 2112;          // 1024

    hipMemsetAsync(ws, 0, 1040 * sizeof(float), stream);

    k_transpose<<<dim3(32, 8), 256, 0, stream>>>(cb, CT);
    k_cnorm<<<4, 256, 0, stream>>>(cb, CN);
    k_zn2<<<256, 256, 0, stream>>>(ze, ZNb, L1b, L1R);
    k_prep_c<<<256, 256, 0, stream>>>(cb, CH);
    k_prep_z<<<dim3(16, 4, 64), 256, 0, stream>>>(ze, ZH, L1R);
    k_margmin<<<dim3(512, 4), 256, 0, stream>>>(ZH, CH, CN, PK1, PK2);
    k_combine4<<<256, 256, 0, stream>>>(PK1, PK2, L1b, L1R, out + O_IDX, counts,
                                        FLAG, CANDLO, CANDHI, flagn, flagnB);
    k_zt<<<dim3(16, 4, 64), 256, 0, stream>>>(ze, ZFLAT);
    k_rescueA<<<1024, 256, 0, stream>>>(ZFLAT, cb, CN, ZNb, FLAG, CANDLO, CANDHI,
                                        flagn, out + O_IDX, counts);
    k_rescueB<<<256, 256, 0, stream>>>(ZFLAT, CT, CN, ZNb, FLAG, flagnB,
                                       out + O_IDX, counts);
    k_ema_cs<<<1, 1024, 0, stream>>>(emacs, counts, out + O_CS, smoothed);
    k_dwsum<<<K_CODES, 256, 0, stream>>>(out + O_IDX, ZFLAT, cb, emadw, smoothed,
                                         out + O_DW, out + O_CB, lossacc);
    k_zq<<<1024, 256, 0, stream>>>(ze, cb, out + O_IDX, out + O_ZQ,
                                   lossacc, out + O_LOSS);
}

// Round 7
// 433.838 us; speedup vs baseline: 1.1172x; 1.1172x over previous
//
#include <hip/hip_runtime.h>
#include <math.h>

// Problem constants
#define K_CODES   1024
#define D_DIM     256
#define HW_SZ     1024          // 32*32
#define N_TOT     65536         // 64 * 1024
#define ND_TOT    16777216.0f   // N_TOT * D_DIM

// Output layout (float32, concatenated in reference return order)
#define O_ZQ    0
#define O_LOSS  16777216
#define O_IDX   16777217
#define O_CB    16842753
#define O_CS    17104897
#define O_DW    17105921

// Scratch inside the O_ZQ region (float units). ALL dead before k_zt
// overwrites the region with zflat.
#define ZHALF_OFF 0           // 65536x256 f16 = 8388608 floats
#define CHALF_OFF 8388608     // 1024x256 f16  = 131072 floats
#define PK2_OFF   8519680     // 4x65536 i32 second-min key partials
#define PK1_OFF   8781824     // 4x65536 i32 min key partials
#define PK3_OFF   9043968     // 4x65536 i32 third-min key partials
#define L1_OFF    9306112     // 65536 f32 row L1 norms (for THR bound)
#define L1R_OFF   9371648     // 65536 f32 actual fp16 residual L1
// Scratch in the O_DW tail (262144 floats, survives k_zt; dead before k_dwsum):
//   ZN     65536 f32 at out+O_DW
//   FLAG   65536 int at +65536   (list A from front, list B from back)
//   CANDLO 65536 int at +131072  (cand0|cand1<<10|cand2<<20 per A entry)
//   CANDHI 65536 int at +196608  (cand3|cand4<<10|cand5<<20 per A entry)

typedef float f2 __attribute__((ext_vector_type(2)));
typedef float f32x4 __attribute__((ext_vector_type(4)));
typedef _Float16 f16;
typedef _Float16 f16x8 __attribute__((ext_vector_type(8)));
typedef _Float16 f16x4 __attribute__((ext_vector_type(4)));

__device__ __forceinline__ int imin(int a, int b) { return a < b ? a : b; }
__device__ __forceinline__ int imax(int a, int b) { return a > b ? a : b; }

// ---------------------------------------------------------------------------
// Transpose codebook [K][D] -> CT [D][K] (for rescueB's streaming rescore).
__global__ void k_transpose(const float* __restrict__ cb, float* __restrict__ ct) {
    __shared__ float tile[32][33];
    int k0 = blockIdx.x * 32;
    int d0 = blockIdx.y * 32;
    int c = threadIdx.x & 31, r0 = threadIdx.x >> 5;
#pragma unroll
    for (int p = 0; p < 4; ++p) {
        int r = r0 + p * 8;
        tile[r][c] = cb[(k0 + r) * D_DIM + d0 + c];
    }
    __syncthreads();
#pragma unroll
    for (int p = 0; p < 4; ++p) {
        int r = r0 + p * 8;
        ct[(size_t)(d0 + r) * K_CODES + k0 + c] = tile[c][r];
    }
}

// ---------------------------------------------------------------------------
// Per-code squared norms, numpy-pairwise fp32 semantics (contract OFF).
__global__ void k_cnorm(const float* __restrict__ cb, float* __restrict__ cn) {
#pragma clang fp contract(off)
    int k = blockIdx.x * 256 + threadIdx.x;            // grid = 4 blocks
    const float* row = cb + (size_t)k * D_DIM;
    float s1 = 0.f, s2 = 0.f;
#pragma unroll
    for (int blk = 0; blk < 2; ++blk) {
        const float* p = row + blk * 128;
        float r[8];
#pragma unroll
        for (int j = 0; j < 8; ++j) { float v = p[j]; r[j] = v * v; }
        for (int i = 8; i < 128; i += 8) {
#pragma unroll
            for (int j = 0; j < 8; ++j) { float v = p[i + j]; r[j] = r[j] + v * v; }
        }
        float s = ((r[0] + r[1]) + (r[2] + r[3])) + ((r[4] + r[5]) + (r[6] + r[7]));
        if (blk == 0) s1 = s; else s2 = s;
    }
    cn[k] = s1 + s2;
}

// ---------------------------------------------------------------------------
// Per-row squared norms (bit-identical fold) + L1 norms (feeds THR bound).
// Also zero-inits the L1R residual accumulator (prep_z atomically adds).
__global__ void k_zn2(const float* __restrict__ ze, float* __restrict__ zn,
                      float* __restrict__ l1, float* __restrict__ l1r) {
#pragma clang fp contract(off)
    int n = blockIdx.x * 256 + threadIdx.x;            // grid = 256 blocks
    int b = n >> 10, hw = n & 1023;
    const float* p = ze + (size_t)b * (D_DIM * HW_SZ) + hw;
    float s1 = 0.f, s2 = 0.f, a1 = 0.f;
#pragma unroll
    for (int blk = 0; blk < 2; ++blk) {
        const float* q = p + (size_t)(blk * 128) * HW_SZ;
        float r[8], qa[8];
#pragma unroll
        for (int j = 0; j < 8; ++j) {
            float v = q[(size_t)j * HW_SZ];
            r[j] = v * v; qa[j] = fabsf(v);
        }
        for (int i = 8; i < 128; i += 8) {
#pragma unroll
            for (int j = 0; j < 8; ++j) {
                float v = q[(size_t)(i + j) * HW_SZ];
                r[j] = r[j] + v * v;
                qa[j] = qa[j] + fabsf(v);
            }
        }
        float s = ((r[0] + r[1]) + (r[2] + r[3])) + ((r[4] + r[5]) + (r[6] + r[7]));
        a1 += ((qa[0] + qa[1]) + (qa[2] + qa[3])) + ((qa[4] + qa[5]) + (qa[6] + qa[7]));
        if (blk == 0) s1 = s; else s2 = s;
    }
    zn[n] = s1 + s2;
    l1[n] = a1;
    l1r[n] = 0.f;
}

// ---------------------------------------------------------------------------
// Codebook -> fp16, scaled by 2^10 (exact pow2; keeps values in [-1,1]).
__global__ __launch_bounds__(256)
void k_prep_c(const float* __restrict__ cb, f16* __restrict__ ch) {
    int i = (blockIdx.x * 256 + threadIdx.x) * 4;      // grid = 256 blocks
    float4 v = *(const float4*)(cb + i);
    f16x4 h;
    h[0] = (f16)(v.x * 1024.0f);
    h[1] = (f16)(v.y * 1024.0f);
    h[2] = (f16)(v.z * 1024.0f);
    h[3] = (f16)(v.w * 1024.0f);
    *(f16x4*)(ch + i) = h;
}

// ---------------------------------------------------------------------------
// z_e [64][256][1024] NCHW -> zhalf [65536][256] row-major fp16.
// Also accumulates the ACTUAL per-row fp16 conversion residual
// L1r(n) = sum_d |z - fl16(z)| (drives the tight rescue threshold).
__global__ __launch_bounds__(256)
void k_prep_z(const float* __restrict__ ze, f16* __restrict__ zh,
              float* __restrict__ l1r) {
    __shared__ float tile[64][65];
    const int t = threadIdx.x;
    const int hw0 = blockIdx.x * 64;
    const int d0  = blockIdx.y * 64;
    const int b   = blockIdx.z;
    const size_t base_in = (size_t)b * (D_DIM * HW_SZ);
#pragma unroll
    for (int p = 0; p < 4; ++p) {
        int dd = p * 16 + (t >> 4);
        int c4 = (t & 15) * 4;
        float4 v = *(const float4*)(ze + base_in + (size_t)(d0 + dd) * HW_SZ + hw0 + c4);
        tile[dd][c4 + 0] = v.x;
        tile[dd][c4 + 1] = v.y;
        tile[dd][c4 + 2] = v.z;
        tile[dd][c4 + 3] = v.w;
    }
    __syncthreads();
#pragma unroll
    for (int p = 0; p < 4; ++p) {
        int hh  = p * 16 + (t >> 4);
        int dc4 = (t & 15) * 4;
        float v0 = tile[dc4 + 0][hh], v1 = tile[dc4 + 1][hh];
        float v2 = tile[dc4 + 2][hh], v3 = tile[dc4 + 3][hh];
        f16x4 h;
        h[0] = (f16)v0; h[1] = (f16)v1; h[2] = (f16)v2; h[3] = (f16)v3;
        *(f16x4*)(zh + (size_t)(b * HW_SZ + hw0 + hh) * D_DIM + d0 + dc4) = h;
        float rs = fabsf(v0 - (float)h[0]) + fabsf(v1 - (float)h[1])
                 + fabsf(v2 - (float)h[2]) + fabsf(v3 - (float)h[3]);
        rs += __shfl_down(rs, 8, 64);
        rs += __shfl_down(rs, 4, 64);
        rs += __shfl_down(rs, 2, 64);
        rs += __shfl_down(rs, 1, 64);
        if ((t & 15) == 0)
            atomicAdd(&l1r[b * HW_SZ + hw0 + hh], rs);
    }
}

// ---------------------------------------------------------------------------
// MFMA argmin: grid = (512 n-tiles, 4 k-chunks). i32 packed-key epilogue,
// now tracking per-row per-chunk TOP-3 keys (m3 gates the full-scan path).
__global__ __launch_bounds__(256, 2)
void k_margmin(const f16* __restrict__ zh, const f16* __restrict__ ch,
               const float* __restrict__ cn,
               int* __restrict__ pk1, int* __restrict__ pk2,
               int* __restrict__ pk3) {
    __shared__ __align__(16) char smem[50688];
    f16* Al = (f16*)smem;               // [128*64] 16 KB
    f16* Bl = (f16*)(smem + 16384);     // [256*64] 32 KB
    const int t  = threadIdx.x;
    const int w  = t >> 6;       // wave (0..3)
    const int l  = t & 63;       // lane
    const int kc = blockIdx.y;   // k-chunk
    const int n0 = blockIdx.x * 128;
    const int rl = l >> 3;       // staging: row-within-8
    const int gg = l & 7;        // staging: granule
    const int gq = l >> 4;       // frag: quarter-wave group
    const int rr = l & 15;       // frag: row/col within frag

    f32x4 acc[8][4];
#pragma unroll
    for (int a = 0; a < 8; ++a)
#pragma unroll
        for (int b = 0; b < 4; ++b) acc[a][b] = (f32x4)0.f;

    for (int d0 = 0; d0 < 256; d0 += 64) {
        __syncthreads();   // previous iteration's frag reads done
        // stage A (z): 128 rows x 64 d, source granule pre-swizzled
#pragma unroll
        for (int i = 0; i < 4; ++i) {
            int row = w * 32 + i * 8 + rl;
            const f16* g = zh + (size_t)(n0 + row) * D_DIM + d0 + 8 * (gg ^ (row & 7));
            __builtin_amdgcn_global_load_lds(
                (const __attribute__((address_space(1))) void*)g,
                (__attribute__((address_space(3))) void*)(smem + (w * 32 + i * 8) * 128),
                16, 0, 0);
        }
        // stage B (codebook): 256 rows x 64 d
#pragma unroll
        for (int i = 0; i < 8; ++i) {
            int row = w * 64 + i * 8 + rl;
            const f16* g = ch + (size_t)(kc * 256 + row) * D_DIM + d0 + 8 * (gg ^ (row & 7));
            __builtin_amdgcn_global_load_lds(
                (const __attribute__((address_space(1))) void*)g,
                (__attribute__((address_space(3))) void*)(smem + 16384 + row * 128),
                16, 0, 0);
        }
        __syncthreads();
#pragma unroll
        for (int ks = 0; ks < 2; ++ks) {
            f16x8 af[8], bf[4];
#pragma unroll
            for (int nf = 0; nf < 8; ++nf) {
                int row = nf * 16 + rr;
                af[nf] = *(const f16x8*)((char*)Al + row * 128 +
                                         16 * ((ks * 4 + gq) ^ (row & 7)));
            }
#pragma unroll
            for (int kf = 0; kf < 4; ++kf) {
                int row = w * 64 + kf * 16 + rr;
                bf[kf] = *(const f16x8*)((char*)Bl + row * 128 +
                                         16 * ((ks * 4 + gq) ^ (row & 7)));
            }
#pragma unroll
            for (int nf = 0; nf < 8; ++nf)
#pragma unroll
                for (int kf = 0; kf < 4; ++kf)
                    acc[nf][kf] = __builtin_amdgcn_mfma_f32_16x16x32_f16(
                        af[nf], bf[kf], acc[nf][kf], 0, 0, 0);
        }
    }
    __syncthreads();   // all frag reads done before smem reuse

    // Epilogue: packed i32 keys + top-3. acc = 1024*G (codebook pre-scale),
    // t*2^21 = cn*2^21 - acc*2^12.  |t| <= 0.49 -> |tq| < 2^21, key fits i32.
    int* ep2 = (int*)smem;               // [128][33] int2 = 33792 B
    int* ep3 = (int*)(smem + 33792);     // [128][33] int  = 16896 B
    float cnq[4];
    int   kk4[4];
#pragma unroll
    for (int kf = 0; kf < 4; ++kf) {
        int k = kc * 256 + w * 64 + kf * 16 + rr;
        kk4[kf] = k;
        cnq[kf] = cn[k] * 0x1p21f;
    }
#pragma unroll
    for (int nf = 0; nf < 8; ++nf) {
#pragma unroll
        for (int r = 0; r < 4; ++r) {
            int m1 = 0x7FFFFFFF, m2 = 0x7FFFFFFF, m3 = 0x7FFFFFFF;
#pragma unroll
            for (int kf = 0; kf < 4; ++kf) {
                float tqf = fmaf(acc[nf][kf][r], -0x1p12f, cnq[kf]);
                int key = ((int)tqf << 10) + kk4[kf];
                int mx1 = imax(m1, key); m1 = imin(m1, key);
                int mx2 = imax(m2, mx1); m2 = imin(m2, mx1);
                m3 = imin(m3, mx2);
            }
            // one xor-step: merge sorted triples of lane pairs (rr even|odd)
            int o1 = __shfl_xor(m1, 1, 64);
            int o2 = __shfl_xor(m2, 1, 64);
            int o3 = __shfl_xor(m3, 1, 64);
            int hi1 = imax(m1, o1); m1 = imin(m1, o1);
            int lo2 = imin(m2, o2); int v = imax(m2, o2);
            int n2  = imin(hi1, lo2); int tt = imax(hi1, lo2);
            int u   = imin(m3, o3);
            m3 = imin(tt, imin(u, v)); m2 = n2;
            if ((rr & 1) == 0) {
                int row = nf * 16 + gq * 4 + r;
                int p   = w * 8 + (rr >> 1);
                *(int2*)&ep2[row * 66 + p * 2] = make_int2(m1, m2);
                ep3[row * 33 + p] = m3;
            }
        }
    }
    __syncthreads();
    if (t < 128) {
        int m1 = 0x7FFFFFFF, m2 = 0x7FFFFFFF, m3 = 0x7FFFFFFF;
        const int2* rp = (const int2*)&ep2[t * 66];
        const int*  r3 = &ep3[t * 33];
#pragma unroll 8
        for (int p = 0; p < 32; ++p) {
            int2 a = rp[p];
            int a3 = r3[p];
            int hi1 = imax(m1, a.x); m1 = imin(m1, a.x);
            int lo2 = imin(m2, a.y); int v = imax(m2, a.y);
            int n2  = imin(hi1, lo2); int tt = imax(hi1, lo2);
            int u   = imin(m3, a3);
            m3 = imin(tt, imin(u, v)); m2 = n2;
        }
        pk1[kc * N_TOT + n0 + t] = m1;
        pk2[kc * N_TOT + n0 + t] = m2;
        pk3[kc * N_TOT + n0 + t] = m3;
    }
}

// ---------------------------------------------------------------------------
// Combine 4 chunk key triples. Outcomes per row:
//   certain: global m2 gap > THR                          -> done
//   cheap A: every chunk m3 gap > THR, <=6 candidates     -> candidates =
//            4 chunk argmins + chunk m2s within THR (sound: rank>=3 codes
//            in chunk c have key >= m3_c > t1+thr)
//   full  B: some chunk m3 within THR (or >6 cands)       -> full 1024 rescue
// THR (sound): l1*1.05e-6 (c-side fp16) + L1r*2.25e-3 (actual z residual)
//             + 2.2e-4 (fold/quant slops).
__global__ __launch_bounds__(256)
void k_combine5(const int* __restrict__ pk1, const int* __restrict__ pk2,
                const int* __restrict__ pk3,
                const float* __restrict__ l1b, const float* __restrict__ l1rb,
                float* __restrict__ out_idx, float* __restrict__ counts,
                int* __restrict__ flag, int* __restrict__ candlo,
                int* __restrict__ candhi,
                int* __restrict__ flagn, int* __restrict__ flagnB) {
    int n = blockIdx.x * 256 + threadIdx.x;
    int a1[4], a2[4], a3[4];
    int m1 = 0x7FFFFFFF, m2 = 0x7FFFFFFF, m3 = 0x7FFFFFFF;
#pragma unroll
    for (int c = 0; c < 4; ++c) {
        a1[c] = pk1[c * N_TOT + n];
        a2[c] = pk2[c * N_TOT + n];
        a3[c] = pk3[c * N_TOT + n];
        int hi1 = imax(m1, a1[c]); m1 = imin(m1, a1[c]);
        int lo2 = imin(m2, a2[c]); int v = imax(m2, a2[c]);
        int n2  = imin(hi1, lo2); int tt = imax(hi1, lo2);
        int u   = imin(m3, a3[c]);
        m3 = imin(tt, imin(u, v)); m2 = n2;
    }
    int i1 = m1 & 1023;
    out_idx[n] = (float)i1;
    atomicAdd(counts + i1, 1.0f);
    int t1 = m1 >> 10;
    float thr = fmaf(l1b[n], 1.05e-6f, fmaf(l1rb[n], 2.25e-3f, 2.2e-4f));
    int thrq = (int)(thr * 0x1p21f);
    if ((m2 >> 10) - t1 > thrq) return;           // certain
    int c0 = a1[0] & 1023, c1 = a1[1] & 1023;
    int c2 = a1[2] & 1023, c3 = a1[3] & 1023;
    int c4 = c0, c5 = c0;                         // pad with duplicates
    int cnt = 4;
    bool B = false;
#pragma unroll
    for (int c = 0; c < 4; ++c) {
        if (((a3[c] >> 10) - t1) <= thrq) { B = true; }
        else if (((a2[c] >> 10) - t1) <= thrq) {
            int idx = a2[c] & 1023;
            if (cnt == 4)      { c4 = idx; cnt = 5; }
            else if (cnt == 5) { c5 = idx; cnt = 6; }
            else B = true;
        }
    }
    if (!B) {
        int p = atomicAdd(flagn, 1);
        flag[p] = n;
        candlo[p] = c0 | (c1 << 10) | (c2 << 20);
        candhi[p] = c3 | (c4 << 10) | (c5 << 20);
    } else {
        int p = atomicAdd(flagnB, 1);
        flag[65535 - p] = n;
    }
}

// ---------------------------------------------------------------------------
// Transpose z_e [64][256][1024] -> zflat [65536][256] (into O_ZQ region,
// overwriting the dead fp16/partial scratch; runs BEFORE the rescues).
__global__ __launch_bounds__(256)
void k_zt(const float* __restrict__ ze, float* __restrict__ zflat) {
    __shared__ float tile[64][65];
    const int t = threadIdx.x;
    const int hw0 = blockIdx.x * 64;
    const int d0  = blockIdx.y * 64;
    const int b   = blockIdx.z;
    const size_t base_in = (size_t)b * (D_DIM * HW_SZ);
#pragma unroll
    for (int p = 0; p < 4; ++p) {
        int dd = p * 16 + (t >> 4);
        int c4 = (t & 15) * 4;
        float4 v = *(const float4*)(ze + base_in + (size_t)(d0 + dd) * HW_SZ + hw0 + c4);
        tile[dd][c4 + 0] = v.x;
        tile[dd][c4 + 1] = v.y;
        tile[dd][c4 + 2] = v.z;
        tile[dd][c4 + 3] = v.w;
    }
    __syncthreads();
#pragma unroll
    for (int p = 0; p < 4; ++p) {
        int hh  = p * 16 + (t >> 4);
        int dc4 = (t & 15) * 4;
        float4 v = { tile[dc4 + 0][hh], tile[dc4 + 1][hh],
                     tile[dc4 + 2][hh], tile[dc4 + 3][hh] };
        *(float4*)(zflat + (size_t)(b * HW_SZ + hw0 + hh) * D_DIM + d0 + dc4) = v;
    }
}

// ---------------------------------------------------------------------------
// Rescue A: exact rescore of the <=6 candidates per flagged row.
// 8 threads per row (slots >5 duplicate cand0 -- harmless under lex min):
// scalar fmaf chain over ascending d (bit-identical exact arithmetic),
// s = fl(zn - 2G) + cn, 3-step shuffle lexicographic (s, k) min.
__global__ __launch_bounds__(256)
void k_rescueA(const float* __restrict__ zflat, const float* __restrict__ cb,
               const float* __restrict__ cn, const float* __restrict__ znb,
               const int* __restrict__ flag, const int* __restrict__ candlo,
               const int* __restrict__ candhi, const int* __restrict__ flagn,
               float* __restrict__ out_idx, float* __restrict__ counts) {
    const int nA = *flagn;
    const int t = threadIdx.x;
    const int s = t & 7;
    const int r = t >> 3;                 // 32 rows per block
    for (int g = blockIdx.x; g * 32 < nA; g += 512) {
        int i = g * 32 + r;
        bool act = i < nA;
        int ii = act ? i : 0;
        int n = flag[ii];
        int lo = candlo[ii], hi = candhi[ii];
        int se = s > 5 ? 0 : s;
        int word = se < 3 ? lo : hi;
        int sh = (se < 3 ? se : se - 3) * 10;
        int k = (word >> sh) & 1023;
        const float* zp = zflat + (size_t)n * D_DIM;
        const float* cp = cb + (size_t)k * D_DIM;
        float acc = 0.f;
        for (int d = 0; d < 256; d += 8) {
            float4 z0 = *(const float4*)(zp + d);
            float4 z1 = *(const float4*)(zp + d + 4);
            float4 cc0 = *(const float4*)(cp + d);
            float4 cc1 = *(const float4*)(cp + d + 4);
            acc = fmaf(z0.x, cc0.x, acc); acc = fmaf(z0.y, cc0.y, acc);
            acc = fmaf(z0.z, cc0.z, acc); acc = fmaf(z0.w, cc0.w, acc);
            acc = fmaf(z1.x, cc1.x, acc); acc = fmaf(z1.y, cc1.y, acc);
            acc = fmaf(z1.z, cc1.z, acc); acc = fmaf(z1.w, cc1.w, acc);
        }
        float sc = (znb[n] - 2.0f * acc) + cn[k];
        // lexicographic min across the 8-lane group
        for (int off = 1; off < 8; off <<= 1) {
            float os = __shfl_xor(sc, off, 64);
            int   ok = __shfl_xor(k, off, 64);
            if (os < sc || (os == sc && ok < k)) { sc = os; k = ok; }
        }
        if (act && s == 0) {
            int old = (int)out_idx[n];
            if (k != old) {
                out_idx[n] = (float)k;
                atomicAdd(counts + old, -1.0f);
                atomicAdd(counts + k,  1.0f);
            }
        }
    }
}

// ---------------------------------------------------------------------------
// Rescue B: full 1024-code exact rescore, ONE ROW PER WAVE (rare rows; shape
// chosen for occupancy/latency, not traffic). Lane l covers codes
// {g*256 + l*4 + q}; 16 fp32 acc/lane; CT reads coalesced (1 KB per quarter
// per d); z broadcast via uniform float4 loads. Per-code chains remain
// sequential fmaf over ascending d -- bit-identical exact arithmetic.
__global__ __launch_bounds__(256)
void k_rescueB(const float* __restrict__ zflat, const float* __restrict__ ct,
               const float* __restrict__ cn, const float* __restrict__ znb,
               const int* __restrict__ flag, const int* __restrict__ flagnB,
               float* __restrict__ out_idx, float* __restrict__ counts) {
    const int t  = threadIdx.x;
    const int wv = t >> 6;
    const int l  = t & 63;
    const int nB = *flagnB;
    for (int i = blockIdx.x * 4 + wv; i < nB; i += 512) {   // grid 128 blocks
        int n = flag[65535 - i];
        const float* zp = zflat + (size_t)n * D_DIM;
        float acc[16];
#pragma unroll
        for (int j = 0; j < 16; ++j) acc[j] = 0.f;
        for (int d4 = 0; d4 < 64; ++d4) {
            float4 zv = *(const float4*)(zp + d4 * 4);   // uniform -> broadcast
#pragma unroll
            for (int j = 0; j < 4; ++j) {
                const float* cp = ct + (size_t)(d4 * 4 + j) * K_CODES + l * 4;
                float4 q0 = *(const float4*)(cp);
                float4 q1 = *(const float4*)(cp + 256);
                float4 q2 = *(const float4*)(cp + 512);
                float4 q3 = *(const float4*)(cp + 768);
                float zd = (j == 0) ? zv.x : (j == 1) ? zv.y : (j == 2) ? zv.z : zv.w;
                acc[0]  = fmaf(zd, q0.x, acc[0]);  acc[1]  = fmaf(zd, q0.y, acc[1]);
                acc[2]  = fmaf(zd, q0.z, acc[2]);  acc[3]  = fmaf(zd, q0.w, acc[3]);
                acc[4]  = fmaf(zd, q1.x, acc[4]);  acc[5]  = fmaf(zd, q1.y, acc[5]);
                acc[6]  = fmaf(zd, q1.z, acc[6]);  acc[7]  = fmaf(zd, q1.w, acc[7]);
                acc[8]  = fmaf(zd, q2.x, acc[8]);  acc[9]  = fmaf(zd, q2.y, acc[9]);
                acc[10] = fmaf(zd, q2.z, acc[10]); acc[11] = fmaf(zd, q2.w, acc[11]);
                acc[12] = fmaf(zd, q3.x, acc[12]); acc[13] = fmaf(zd, q3.y, acc[13]);
                acc[14] = fmaf(zd, q3.z, acc[14]); acc[15] = fmaf(zd, q3.w, acc[15]);
            }
        }
        float znv = znb[n];
        float bs = INFINITY; int bk = 0;
#pragma unroll
        for (int g = 0; g < 4; ++g) {
            float4 cnv = *(const float4*)(cn + g * 256 + l * 4);
#pragma unroll
            for (int q = 0; q < 4; ++q) {
                int k = g * 256 + l * 4 + q;
                float cna = (q == 0) ? cnv.x : (q == 1) ? cnv.y : (q == 2) ? cnv.z : cnv.w;
                float sc = (znv - 2.0f * acc[g * 4 + q]) + cna;
                if (sc < bs || (sc == bs && k < bk)) { bs = sc; bk = k; }
            }
        }
        for (int off = 1; off < 64; off <<= 1) {
            float os = __shfl_xor(bs, off, 64);
            int   ok = __shfl_xor(bk, off, 64);
            if (os < bs || (os == bs && ok < bk)) { bs = os; bk = ok; }
        }
        if (l == 0) {
            int old = (int)out_idx[n];
            if (old != bk) {
                out_idx[n] = (float)bk;
                atomicAdd(counts + old, -1.0f);
                atomicAdd(counts + bk,  1.0f);
            }
        }
    }
}

// ---------------------------------------------------------------------------
// EMA cluster size + smoothed (loss finalize lives in k_zq).
__global__ __launch_bounds__(1024)
void k_ema_cs(const float* __restrict__ ema_cs, const float* __restrict__ counts,
              float* __restrict__ out_cs, float* __restrict__ smoothed) {
    __shared__ float red[1024];
    int k = threadIdx.x;
    float cs_new = fmaf(0.99f, ema_cs[k], 0.01f * counts[k]);
    red[k] = cs_new;
    __syncthreads();
    for (int off = 512; off > 0; off >>= 1) {
        if (k < off) red[k] += red[k + off];
        __syncthreads();
    }
    float ntot = red[0];
    out_cs[k] = cs_new;
    smoothed[k] = (cs_new + 1e-5f) / (ntot + 0.01024f) * ntot;
}

// ---------------------------------------------------------------------------
// Per-code segment sum: one block per code; compact matching rows into an LDS
// queue (float4 index scan), sum rows coalesced from zflat with 2-way load
// ILP. Fuses loss partials + dw EMA + cb write.
__global__ __launch_bounds__(256)
void k_dwsum(const float* __restrict__ idxf, const float* __restrict__ zflat,
             const float* __restrict__ cb, const float* __restrict__ ema_dw,
             const float* __restrict__ smoothed, float* __restrict__ out_dw,
             float* __restrict__ out_cb, float* __restrict__ lossacc) {
    __shared__ int queue[4096];
    __shared__ int qn;
    __shared__ float lred[4];

    const int k = blockIdx.x;
    const int t = threadIdx.x;
    const float fk = (float)k;
    const float ck = cb[(size_t)k * D_DIM + t];

    float acc = 0.f;
    float ls  = 0.f;

    for (int chunk = 0; chunk < 16; ++chunk) {
        if (t == 0) qn = 0;
        __syncthreads();
#pragma unroll
        for (int j = 0; j < 4; ++j) {
            int nb = chunk * 4096 + j * 1024 + t * 4;   // coalesced float4 scan
            float4 iv = *(const float4*)(idxf + nb);
            if (iv.x == fk) { int p = atomicAdd(&qn, 1); queue[p] = nb; }
            if (iv.y == fk) { int p = atomicAdd(&qn, 1); queue[p] = nb + 1; }
            if (iv.z == fk) { int p = atomicAdd(&qn, 1); queue[p] = nb + 2; }
            if (iv.w == fk) { int p = atomicAdd(&qn, 1); queue[p] = nb + 3; }
        }
        __syncthreads();
        int m = qn;
        int i = 0;
        for (; i + 1 < m; i += 2) {                    // 2-way load ILP
            int n1 = queue[i], n2 = queue[i + 1];
            float z1 = zflat[(size_t)n1 * D_DIM + t];
            float z2 = zflat[(size_t)n2 * D_DIM + t];
            acc += z1; float d1 = ck - z1; ls += d1 * d1;
            acc += z2; float d2 = ck - z2; ls += d2 * d2;
        }
        if (i < m) {
            int n1 = queue[i];
            float z1 = zflat[(size_t)n1 * D_DIM + t];
            acc += z1; float d1 = ck - z1; ls += d1 * d1;
        }
        __syncthreads();   // all queue reads done before next chunk's writes
    }

    size_t o = (size_t)k * D_DIM + t;
    float nd = fmaf(0.99f, ema_dw[o], 0.01f * acc);
    out_dw[o] = nd;
    out_cb[o] = nd / smoothed[k];

#pragma unroll
    for (int off = 32; off > 0; off >>= 1) ls += __shfl_down(ls, off, 64);
    if ((t & 63) == 0) lred[t >> 6] = ls;
    __syncthreads();
    if (t == 0) atomicAdd(lossacc, lred[0] + lred[1] + lred[2] + lred[3]);
}

// ---------------------------------------------------------------------------
// Straight-through z_q writer: pure float4 stream + L2 codebook gather.
// Grid 1024 blocks; each block covers a 16-d slice.
__global__ __launch_bounds__(256)
void k_zq(const float* __restrict__ ze, const float* __restrict__ cb,
          const float* __restrict__ idxf, float* __restrict__ out0,
          const float* __restrict__ lossacc, float* __restrict__ out_loss) {
    const int t = threadIdx.x;
    int q   = blockIdx.x & 3;                  // d-16 segment
    int g   = (blockIdx.x >> 2) * 64 + (t & 63);   // hw4-group id in [0, 16384)
    int b   = g >> 8;
    int hwl = (g & 255) * 4;
    int dg  = t >> 6;                          // d-quarter (0..3)
    const size_t base = (size_t)b * (D_DIM * HW_SZ) + hwl;

    int i0 = (int)idxf[b * HW_SZ + hwl + 0];
    int i1 = (int)idxf[b * HW_SZ + hwl + 1];
    int i2 = (int)idxf[b * HW_SZ + hwl + 2];
    int i3 = (int)idxf[b * HW_SZ + hwl + 3];
    const float* c0 = cb + (size_t)i0 * D_DIM;
    const float* c1 = cb + (size_t)i1 * D_DIM;
    const float* c2 = cb + (size_t)i2 * D_DIM;
    const float* c3 = cb + (size_t)i3 * D_DIM;

#pragma unroll 4
    for (int i = 0; i < 16; ++i) {
        int d = dg * 64 + q * 16 + i;
        size_t o = base + (size_t)d * HW_SZ;
        float4 z = *(const float4*)(ze + o);
        float4 r;
        r.x = z.x + (c0[d] - z.x);
        r.y = z.y + (c1[d] - z.y);
        r.z = z.z + (c2[d] - z.z);
        r.w = z.w + (c3[d] - z.w);
        *(float4*)(out0 + o) = r;
    }

    if (blockIdx.x == 0 && t == 0)
        out_loss[0] = 0.5f * lossacc[0] / ND_TOT;
}

// ---------------------------------------------------------------------------
extern "C" void kernel_launch(void* const* d_in, const int* in_sizes, int n_in,
                              void* d_out, int out_size, void* d_ws, size_t ws_size,
                              hipStream_t stream) {
    const float* ze     = (const float*)d_in[0];  // [64,256,32,32]
    const float* cb     = (const float*)d_in[1];  // [1024,256]
    const float* emacs  = (const float*)d_in[2];  // [1024]
    const float* emadw  = (const float*)d_in[3];  // [1024,256]
    float* out = (float*)d_out;
    float* ws  = (float*)d_ws;

    // Scratch choreography (stream-ordered reuse of d_out):
    //   O_ZQ region: ZH/CH (prep -> margmin), PK1/PK2/PK3 (margmin ->
    //     combine5), L1/L1R (zn2/prep_z -> combine5) — dead before k_zt;
    //     zflat (zt -> rescueA/B/dwsum) — overwritten by k_zq at the end.
    //   Tail O_CB: CT (transpose -> rescueB, then out_cb by dwsum).
    //   Tail O_DW (262144 = 4x65536): ZN | FLAG(A front/B back) | CANDLO |
    //     CANDHI (combine5 -> rescueA/B, then out_dw by dwsum).
    f16*   ZH     = (f16*)(out + ZHALF_OFF);
    f16*   CH     = (f16*)(out + CHALF_OFF);
    int*   PK2    = (int*)(out + PK2_OFF);
    int*   PK1    = (int*)(out + PK1_OFF);
    int*   PK3    = (int*)(out + PK3_OFF);
    float* L1b    = out + L1_OFF;
    float* L1R    = out + L1R_OFF;
    float* ZFLAT  = out;
    float* CT     = out + O_CB;
    float* ZNb    = out + O_DW;
    int*   FLAG   = (int*)(out + O_DW + 65536);
    int*   CANDLO = (int*)(out + O_DW + 131072);
    int*   CANDHI = (int*)(out + O_DW + 196608);
    // d_ws scratch
    float* counts   = ws;                 // 1024
    float* lossacc  = ws + 1024;          // 1
    int*   flagn    = (int*)(ws + 1025);  // 1
    int*   flagnB   = (int*)(ws + 1026);  // 1
    float* smoothed = ws + 1088;          // 1024
    float* CN       = ws + 2112;          // 1024

    hipMemsetAsync(ws, 0, 1040 * sizeof(float), stream);

    k_transpose<<<dim3(32, 8), 256, 0, stream>>>(cb, CT);
    k_cnorm<<<4, 256, 0, stream>>>(cb, CN);
    k_zn2<<<256, 256, 0, stream>>>(ze, ZNb, L1b, L1R);
    k_prep_c<<<256, 256, 0, stream>>>(cb, CH);
    k_prep_z<<<dim3(16, 4, 64), 256, 0, stream>>>(ze, ZH, L1R);
    k_margmin<<<dim3(512, 4), 256, 0, stream>>>(ZH, CH, CN, PK1, PK2, PK3);
    k_combine5<<<256, 256, 0, stream>>>(PK1, PK2, PK3, L1b, L1R, out + O_IDX,
                                        counts, FLAG, CANDLO, CANDHI,
                                        flagn, flagnB);
    k_zt<<<dim3(16, 4, 64), 256, 0, stream>>>(ze, ZFLAT);
    k_rescueA<<<512, 256, 0, stream>>>(ZFLAT, cb, CN, ZNb, FLAG, CANDLO, CANDHI,
                                       flagn, out + O_IDX, counts);
    k_rescueB<<<128, 256, 0, stream>>>(ZFLAT, CT, CN, ZNb, FLAG, flagnB,
                                       out + O_IDX, counts);
    k_ema_cs<<<1, 1024, 0, stream>>>(emacs, counts, out + O_CS, smoothed);
    k_dwsum<<<K_CODES, 256, 0, stream>>>(out + O_IDX, ZFLAT, cb, emadw, smoothed,
                                         out + O_DW, out + O_CB, lossacc);
    k_zq<<<1024, 256, 0, stream>>>(ze, cb, out + O_IDX, out + O_ZQ,
                                   lossacc, out + O_LOSS);
}